// Round 4
// baseline (354.105 us; speedup 1.0000x reference)
//
#include <hip/hip_runtime.h>
#include <hip/hip_bf16.h>

typedef unsigned short u16;
typedef __attribute__((ext_vector_type(8))) __bf16 bf16x8;
typedef __attribute__((ext_vector_type(4))) float f32x4;

#define DEV static __device__ __forceinline__

DEV u16 f2bf(float f) {
  union { float f; unsigned u; } c; c.f = f;
  unsigned r = c.u + 0x7fffu + ((c.u >> 16) & 1u);
  return (u16)(r >> 16);
}
DEV float fsig(float x) { return 1.f / (1.f + __expf(-x)); }

DEV void gload_lds16(const void* g, void* l) {
  __builtin_amdgcn_global_load_lds(
      (const __attribute__((address_space(1))) void*)g,
      (__attribute__((address_space(3))) void*)l, 16, 0, 0);
}

// fp32 -> bf16 elementwise (RNE), float4-vectorized
__global__ void cvt_bf16(const float4* __restrict__ src, u16* __restrict__ dst, int n4) {
  int i = blockIdx.x * blockDim.x + threadIdx.x;
  int stride = gridDim.x * blockDim.x;
  for (; i < n4; i += stride) {
    float4 v = src[i];
    union { u16 s[4]; unsigned long long q; } o;
    o.s[0] = f2bf(v.x); o.s[1] = f2bf(v.y); o.s[2] = f2bf(v.z); o.s[3] = f2bf(v.w);
    *(unsigned long long*)&dst[(size_t)i * 4] = o.q;
  }
}

__global__ void cvt_w3(const float4* __restrict__ s0, const float4* __restrict__ s1,
                       const float4* __restrict__ s2, u16* __restrict__ dst, int n4) {
  const float4* src = blockIdx.z == 0 ? s0 : (blockIdx.z == 1 ? s1 : s2);
  u16* d = dst + (size_t)blockIdx.z * n4 * 4;
  int i = blockIdx.x * blockDim.x + threadIdx.x;
  int stride = gridDim.x * blockDim.x;
  for (; i < n4; i += stride) {
    float4 v = src[i];
    union { u16 s[4]; unsigned long long q; } o;
    o.s[0] = f2bf(v.x); o.s[1] = f2bf(v.y); o.s[2] = f2bf(v.z); o.s[3] = f2bf(v.w);
    *(unsigned long long*)&d[(size_t)i * 4] = o.q;
  }
}

// 64x64-tile bf16 transpose: VT[d][k] = V[k][d], per batch (blockIdx.z)
__global__ __launch_bounds__(256) void transpose_bf16(
    const u16* __restrict__ V, u16* __restrict__ VT, int rows, int cols) {
  __shared__ u16 t[64][80];
  const u16* Vb = V + (size_t)blockIdx.z * rows * cols;
  u16* VTb = VT + (size_t)blockIdx.z * rows * cols;
  const int kb = blockIdx.x * 64, db = blockIdx.y * 64;
  const int tid = threadIdx.x;
  const int r = tid >> 3, c8 = (tid & 7) * 8;
#pragma unroll
  for (int it = 0; it < 2; it++) {
    int rr = r + it * 32;
    *(uint4*)&t[rr][c8] = *(const uint4*)&Vb[(size_t)(kb + rr) * cols + db + c8];
  }
  __syncthreads();
#pragma unroll
  for (int it = 0; it < 2; it++) {
    int d = (tid >> 3) + it * 32;
    int k0 = (tid & 7) * 8;
    union { u16 s[8]; uint4 q; } o;
#pragma unroll
    for (int j = 0; j < 8; j++) o.s[j] = t[k0 + j][d];
    *(uint4*)&VTb[(size_t)(db + d) * rows + kb + k0] = o.q;
  }
}

// ---------- 128^2 m97-structure GEMM (QKV and PV) ----------
template <int EPI>
__global__ __launch_bounds__(256, 2) void gemm_bt(
    const u16* __restrict__ A, const u16* __restrict__ Bt,
    u16* __restrict__ Cb, float* __restrict__ Cf,
    const float* __restrict__ bias0, const float* __restrict__ bias1,
    const float* __restrict__ bias2,
    int M, int N, int K) {
  __shared__ __align__(16) u16 As[128 * 64];
  __shared__ __align__(16) u16 Bs[128 * 64];

  const int bm = blockIdx.x, bn = blockIdx.y, z = blockIdx.z;
  if (EPI == 0) {
    Bt += (size_t)z * N * K;
  } else {
    A += (size_t)z * M * K;
    Bt += (size_t)z * N * K;
  }
  const size_t cofs = (size_t)z * M * N;
  const float* bias = (EPI == 0) ? (z == 0 ? bias0 : (z == 1 ? bias1 : bias2)) : nullptr;
  const float scale = (EPI == 0 && z == 0) ? 0.03125f : 1.0f;

  const int tid = threadIdx.x;
  const int wid = tid >> 6, lane = tid & 63;
  const int wr = wid >> 1, wc = wid & 1;
  const int l3 = lane >> 3, sl = lane & 7;
  const int srcslot = sl ^ l3;

  const u16* Ag = A + (size_t)(bm * 128 + wid * 32 + l3) * K + srcslot * 8;
  const u16* Bg = Bt + (size_t)(bn * 128 + wid * 32 + l3) * K + srcslot * 8;
  u16* AsW = &As[wid * 32 * 64];
  u16* BsW = &Bs[wid * 32 * 64];

  f32x4 acc[4][4];
#pragma unroll
  for (int i = 0; i < 4; i++)
#pragma unroll
    for (int j = 0; j < 4; j++) acc[i][j] = (f32x4)(0.f);

  const int fr = lane & 15, kq = lane >> 4;

  for (int kt = 0; kt < K; kt += 64) {
#pragma unroll
    for (int i = 0; i < 4; i++) {
      gload_lds16(Ag + kt + i * 8 * K, AsW + i * 8 * 64);
      gload_lds16(Bg + kt + i * 8 * K, BsW + i * 8 * 64);
    }
    __syncthreads();
#pragma unroll
    for (int ks = 0; ks < 2; ks++) {
      bf16x8 af[4], bfr[4];
#pragma unroll
      for (int i = 0; i < 4; i++) {
        const int ra = wr * 64 + i * 16 + fr;
        af[i] = *(const bf16x8*)&As[ra * 64 + (((ks * 4 + kq) ^ (ra & 7)) * 8)];
        const int rb = wc * 64 + i * 16 + fr;
        bfr[i] = *(const bf16x8*)&Bs[rb * 64 + (((ks * 4 + kq) ^ (rb & 7)) * 8)];
      }
#pragma unroll
      for (int i = 0; i < 4; i++)
#pragma unroll
        for (int j = 0; j < 4; j++)
          acc[i][j] = __builtin_amdgcn_mfma_f32_16x16x32_bf16(af[i], bfr[j], acc[i][j], 0, 0, 0);
    }
    __syncthreads();
  }

  const int rbase = bm * 128 + wr * 64;
  const int cbase = bn * 128 + wc * 64;
#pragma unroll
  for (int i = 0; i < 4; i++)
#pragma unroll
    for (int j = 0; j < 4; j++) {
      const int col = cbase + j * 16 + fr;
#pragma unroll
      for (int r = 0; r < 4; r++) {
        const int row = rbase + i * 16 + kq * 4 + r;
        float v = acc[i][j][r];
        if (EPI == 0) {
          v = (v + bias[col]) * scale;
          Cb[cofs + (size_t)row * N + col] = f2bf(v);
        } else {
          Cf[cofs + (size_t)row * N + col] = v;
        }
      }
    }
}

// ---------- scores: 256x256-tile, BK=64, 8-wave, 8-phase counted-vmcnt ----------
// P = sigmoid(sigmoid(Q*K^T)*mask), Q pre-scaled by 1/32. z = batch.
// Epilogue: per-wave LDS transpose -> vectorized mask load + packed bf16 store.
__global__ __launch_bounds__(512, 2) void scores256(
    const u16* __restrict__ Qg, const u16* __restrict__ Kg,
    u16* __restrict__ Pg, const float* __restrict__ maskg) {
  constexpr int S = 4096, DK = 1024;
  __shared__ __align__(16) u16 lds[2][2][2][128 * 64];  // 128 KiB

  // T1 bijective XCD swizzle within each batch plane (256 tiles, 256%8==0)
  const int orig = blockIdx.x + (blockIdx.y << 4);
  const int logical = (orig & 7) * 32 + (orig >> 3);
  const int bm = logical >> 4, bn = logical & 15;
  const int z = blockIdx.z;

  const u16* A = Qg + (size_t)z * S * DK;
  const u16* Bt = Kg + (size_t)z * S * DK;
  const float* mask = maskg + (size_t)z * S * S;
  u16* Cb = Pg + (size_t)z * S * S;

  const int tid = threadIdx.x;
  const int wid = tid >> 6, lane = tid & 63;
  const int wr = wid >> 2, wc = wid & 3;      // 2x4 wave grid; wave tile 128x64
  const int fr = lane & 15, kq = lane >> 4;

  const int srow = (wid << 3) + (lane >> 3);  // staging row (+64 per issue)
  const int sslot = lane & 7;
  const int arow0 = bm * 256, brow0 = bn * 256;

  f32x4 acc[8][4];
#pragma unroll
  for (int i = 0; i < 8; i++)
#pragma unroll
    for (int j = 0; j < 4; j++) acc[i][j] = (f32x4)(0.f);
  bf16x8 a_[4][2], b_[4][2];

#define STAGE(bf, ab, hf, kt_) do {                                         \
    const u16* gp_ = (ab) ? Bt : A;                                         \
    const int rb_ = ((ab) ? brow0 : arow0) + (hf) * 128;                    \
    _Pragma("unroll")                                                       \
    for (int ii_ = 0; ii_ < 2; ii_++) {                                     \
      const int row_ = srow + ii_ * 64;                                     \
      const int c8_ = sslot ^ (row_ & 7);                                   \
      gload_lds16(gp_ + (size_t)(rb_ + row_) * DK + (kt_) + c8_ * 8,        \
                  &lds[bf][ab][hf][wid * 512 + ii_ * 4096]);                \
    }                                                                       \
  } while (0)

#define LDA_(bf, i_, kk_)                                                   \
  (*(const bf16x8*)&lds[bf][0][wr][((i_) * 16 + fr) * 64 +                  \
      ((((kk_) * 4 + kq) ^ (((i_) * 16 + fr) & 7)) * 8)])
#define LDB_(bf, j_, kk_)                                                   \
  (*(const bf16x8*)&lds[bf][1][wc >> 1][((wc & 1) * 64 + (j_) * 16 + fr) * 64 + \
      ((((kk_) * 4 + kq) ^ (((wc & 1) * 64 + (j_) * 16 + fr) & 7)) * 8)])

#define DSA(bf, ih) do {                                                    \
    _Pragma("unroll") for (int i_ = 0; i_ < 4; i_++)                        \
    _Pragma("unroll") for (int k_ = 0; k_ < 2; k_++)                        \
      a_[i_][k_] = LDA_(bf, (ih) + i_, k_);                                 \
  } while (0)
#define DSB(bf, jp) do {                                                    \
    _Pragma("unroll") for (int j_ = 0; j_ < 2; j_++)                        \
    _Pragma("unroll") for (int k_ = 0; k_ < 2; k_++)                        \
      b_[(jp) + j_][k_] = LDB_(bf, (jp) + j_, k_);                          \
  } while (0)
#define MF(ih, jp) do {                                                     \
    _Pragma("unroll") for (int i_ = 0; i_ < 4; i_++)                        \
    _Pragma("unroll") for (int j_ = 0; j_ < 2; j_++)                        \
    _Pragma("unroll") for (int k_ = 0; k_ < 2; k_++)                        \
      acc[(ih) + i_][(jp) + j_] = __builtin_amdgcn_mfma_f32_16x16x32_bf16(  \
          a_[i_][k_], b_[(jp) + j_][k_], acc[(ih) + i_][(jp) + j_], 0, 0, 0); \
  } while (0)
#define BAR() __builtin_amdgcn_s_barrier()
#define LGKM0() asm volatile("s_waitcnt lgkmcnt(0)" ::: "memory")
#define VMC4() asm volatile("s_waitcnt vmcnt(4)" ::: "memory")

  // prologue: tile0 full (A0,A1,B0,B1) + tile1 (B0,B1); drain to 4
  STAGE(0, 0, 0, 0); STAGE(0, 0, 1, 0); STAGE(0, 1, 0, 0); STAGE(0, 1, 1, 0);
  STAGE(1, 1, 0, 64); STAGE(1, 1, 1, 64);
  VMC4();
  BAR();

  constexpr int NIT = DK / 128;  // 8 iterations, 2 K-tiles each
#pragma unroll 1
  for (int t = 0; t < NIT; t++) {
    const int ktv = t * 128 + 64;
    const int kt2 = (t * 128 + 128 < DK) ? t * 128 + 128 : DK - 64;  // clamp tail
    const int kt3 = (t * 128 + 192 < DK) ? t * 128 + 192 : DK - 64;

    // --- tile u = 2t (buf0) ---
    DSA(0, 0); DSB(0, 0);
    STAGE(1, 0, 0, ktv);
    BAR(); LGKM0();
    __builtin_amdgcn_s_setprio(1); MF(0, 0); __builtin_amdgcn_s_setprio(0);
    BAR();
    DSB(0, 2);
    STAGE(1, 0, 1, ktv);
    BAR(); LGKM0();
    __builtin_amdgcn_s_setprio(1); MF(0, 2); __builtin_amdgcn_s_setprio(0);
    BAR();
    DSA(0, 4);
    STAGE(0, 1, 0, kt2);
    BAR(); LGKM0();
    __builtin_amdgcn_s_setprio(1); MF(4, 2); __builtin_amdgcn_s_setprio(0);
    BAR();
    STAGE(0, 1, 1, kt2);
    BAR(); LGKM0();
    __builtin_amdgcn_s_setprio(1); MF(4, 0); __builtin_amdgcn_s_setprio(0);
    VMC4();
    BAR();
    // --- tile v = 2t+1 (buf1) ---
    DSA(1, 0); DSB(1, 0);
    STAGE(0, 0, 0, kt2);
    BAR(); LGKM0();
    __builtin_amdgcn_s_setprio(1); MF(0, 0); __builtin_amdgcn_s_setprio(0);
    BAR();
    DSB(1, 2);
    STAGE(0, 0, 1, kt2);
    BAR(); LGKM0();
    __builtin_amdgcn_s_setprio(1); MF(0, 2); __builtin_amdgcn_s_setprio(0);
    BAR();
    DSA(1, 4);
    STAGE(1, 1, 0, kt3);
    BAR(); LGKM0();
    __builtin_amdgcn_s_setprio(1); MF(4, 2); __builtin_amdgcn_s_setprio(0);
    BAR();
    STAGE(1, 1, 1, kt3);
    BAR(); LGKM0();
    __builtin_amdgcn_s_setprio(1); MF(4, 0); __builtin_amdgcn_s_setprio(0);
    VMC4();
    BAR();
  }

  // ---- epilogue: drain staging, repurpose LDS as per-wave fp32 transpose ----
  asm volatile("s_waitcnt vmcnt(0)" ::: "memory");
  BAR();

  float* wlds = (float*)lds + wid * 4096;  // 64x64 f32 per wave (16 KiB)
  const int rr = lane >> 4, cc = lane & 15;
  const int rbase = bm * 256 + wr * 128;
  const int cbase = bn * 256 + wc * 64;

#pragma unroll 1
  for (int p = 0; p < 2; p++) {
    // transpose-write: acc rows i = p*4 .. p*4+3 (64 rows x 64 cols)
#pragma unroll
    for (int ii = 0; ii < 4; ii++)
#pragma unroll
      for (int j = 0; j < 4; j++)
#pragma unroll
        for (int r = 0; r < 4; r++) {
          const int row = ii * 16 + kq * 4 + r;
          const int col = (j * 16 + fr) ^ ((row & 7) << 2);
          wlds[row * 64 + col] = acc[p * 4 + ii][j][r];
        }
    // (compiler orders ds_write->ds_read via lgkmcnt; reads below alias wlds)
#pragma unroll 8
    for (int rg = 0; rg < 16; rg++) {
      const int row = rg * 4 + rr;
      const int colp = (cc * 4) ^ ((row & 7) << 2);
      f32x4 s = *(f32x4*)&wlds[row * 64 + colp];
      const int grow = rbase + p * 64 + row;
      const int gcol = cbase + cc * 4;
      const float4 m = *(const float4*)&mask[(size_t)grow * S + gcol];
      union { u16 h[4]; unsigned long long q; } o;
      o.h[0] = f2bf(fsig(fsig(s[0]) * m.x));
      o.h[1] = f2bf(fsig(fsig(s[1]) * m.y));
      o.h[2] = f2bf(fsig(fsig(s[2]) * m.z));
      o.h[3] = f2bf(fsig(fsig(s[3]) * m.w));
      *(unsigned long long*)&Cb[(size_t)grow * S + gcol] = o.q;
    }
  }
#undef STAGE
#undef LDA_
#undef LDB_
#undef DSA
#undef DSB
#undef MF
#undef BAR
#undef LGKM0
#undef VMC4
}

extern "C" void kernel_launch(void* const* d_in, const int* in_sizes, int n_in,
                              void* d_out, int out_size, void* d_ws, size_t ws_size,
                              hipStream_t stream) {
  const int B = 2, S = 4096, D = 1024;
  const float* hid  = (const float*)d_in[0];
  const float* mask = (const float*)d_in[1];
  const float* Wq = (const float*)d_in[2];
  const float* bq = (const float*)d_in[3];
  const float* Wk = (const float*)d_in[4];
  const float* bk = (const float*)d_in[5];
  const float* Wv = (const float*)d_in[6];
  const float* bv = (const float*)d_in[7];

  const size_t MT = (size_t)B * S * D;  // 8388608
  u16* hbf = (u16*)d_ws;                // MT
  u16* wbf = hbf + MT;                  // 3*D*D
  u16* Qb  = wbf + 3 * (size_t)D * D;   // MT  (Q,K,V contiguous: EPI0 z-offset)
  u16* Kb  = Qb + MT;
  u16* Vb  = Kb + MT;
  u16* VTb = Vb + MT;                   // MT
  u16* Pb  = VTb + MT;                  // B*S*S

  // 1. converts
  cvt_bf16<<<2048, 256, 0, stream>>>((const float4*)hid, hbf, (int)(MT / 4));
  cvt_w3<<<dim3(512, 1, 3), 256, 0, stream>>>(
      (const float4*)Wq, (const float4*)Wk, (const float4*)Wv, wbf, D * D / 4);

  // 2. fused QKV projection
  gemm_bt<0><<<dim3(B * S / 128, D / 128, 3), 256, 0, stream>>>(
      hbf, wbf, Qb, nullptr, bq, bk, bv, B * S, D, D);

  // 3. V transpose per batch
  transpose_bf16<<<dim3(S / 64, D / 64, B), 256, 0, stream>>>(Vb, VTb, S, D);

  // 4. scores (256^2 8-phase + vectorized epilogue), both batches
  scores256<<<dim3(S / 256, S / 256, B), 512, 0, stream>>>(Qb, Kb, Pb, mask);

  // 5. P*V
  gemm_bt<2><<<dim3(S / 128, D / 128, B), 256, 0, stream>>>(
      Pb, VTb, nullptr, (float*)d_out, nullptr, nullptr, nullptr, S, D, S);
}

// Round 6
// 256.308 us; speedup vs baseline: 1.3816x; 1.3816x over previous
//
#include <hip/hip_runtime.h>
#include <hip/hip_bf16.h>

typedef unsigned short u16;
typedef __attribute__((ext_vector_type(8))) __bf16 bf16x8;
typedef __attribute__((ext_vector_type(4))) float f32x4;

#define DEV static __device__ __forceinline__

DEV u16 f2bf(float f) {
  union { float f; unsigned u; } c; c.f = f;
  unsigned r = c.u + 0x7fffu + ((c.u >> 16) & 1u);
  return (u16)(r >> 16);
}
DEV float fsig(float x) { return 1.f / (1.f + __expf(-x)); }

DEV void gload_lds16(const void* g, void* l) {
  __builtin_amdgcn_global_load_lds(
      (const __attribute__((address_space(1))) void*)g,
      (__attribute__((address_space(3))) void*)l, 16, 0, 0);
}

// fp32 -> bf16 elementwise (RNE), float4-vectorized
__global__ void cvt_bf16(const float4* __restrict__ src, u16* __restrict__ dst, int n4) {
  int i = blockIdx.x * blockDim.x + threadIdx.x;
  int stride = gridDim.x * blockDim.x;
  for (; i < n4; i += stride) {
    float4 v = src[i];
    union { u16 s[4]; unsigned long long q; } o;
    o.s[0] = f2bf(v.x); o.s[1] = f2bf(v.y); o.s[2] = f2bf(v.z); o.s[3] = f2bf(v.w);
    *(unsigned long long*)&dst[(size_t)i * 4] = o.q;
  }
}

__global__ void cvt_w3(const float4* __restrict__ s0, const float4* __restrict__ s1,
                       const float4* __restrict__ s2, u16* __restrict__ dst, int n4) {
  const float4* src = blockIdx.z == 0 ? s0 : (blockIdx.z == 1 ? s1 : s2);
  u16* d = dst + (size_t)blockIdx.z * n4 * 4;
  int i = blockIdx.x * blockDim.x + threadIdx.x;
  int stride = gridDim.x * blockDim.x;
  for (; i < n4; i += stride) {
    float4 v = src[i];
    union { u16 s[4]; unsigned long long q; } o;
    o.s[0] = f2bf(v.x); o.s[1] = f2bf(v.y); o.s[2] = f2bf(v.z); o.s[3] = f2bf(v.w);
    *(unsigned long long*)&d[(size_t)i * 4] = o.q;
  }
}

// 64x64-tile bf16 transpose: VT[d][k] = V[k][d], per batch (blockIdx.z)
__global__ __launch_bounds__(256) void transpose_bf16(
    const u16* __restrict__ V, u16* __restrict__ VT, int rows, int cols) {
  __shared__ u16 t[64][80];
  const u16* Vb = V + (size_t)blockIdx.z * rows * cols;
  u16* VTb = VT + (size_t)blockIdx.z * rows * cols;
  const int kb = blockIdx.x * 64, db = blockIdx.y * 64;
  const int tid = threadIdx.x;
  const int r = tid >> 3, c8 = (tid & 7) * 8;
#pragma unroll
  for (int it = 0; it < 2; it++) {
    int rr = r + it * 32;
    *(uint4*)&t[rr][c8] = *(const uint4*)&Vb[(size_t)(kb + rr) * cols + db + c8];
  }
  __syncthreads();
#pragma unroll
  for (int it = 0; it < 2; it++) {
    int d = (tid >> 3) + it * 32;
    int k0 = (tid & 7) * 8;
    union { u16 s[8]; uint4 q; } o;
#pragma unroll
    for (int j = 0; j < 8; j++) o.s[j] = t[k0 + j][d];
    *(uint4*)&VTb[(size_t)(db + d) * rows + kb + k0] = o.q;
  }
}

// ---------- 128^2 m97-structure GEMM (QKV and PV) ----------
template <int EPI>
__global__ __launch_bounds__(256, 2) void gemm_bt(
    const u16* __restrict__ A, const u16* __restrict__ Bt,
    u16* __restrict__ Cb, float* __restrict__ Cf,
    const float* __restrict__ bias0, const float* __restrict__ bias1,
    const float* __restrict__ bias2,
    int M, int N, int K) {
  __shared__ __align__(16) u16 As[128 * 64];
  __shared__ __align__(16) u16 Bs[128 * 64];

  const int bm = blockIdx.x, bn = blockIdx.y, z = blockIdx.z;
  if (EPI == 0) {
    Bt += (size_t)z * N * K;
  } else {
    A += (size_t)z * M * K;
    Bt += (size_t)z * N * K;
  }
  const size_t cofs = (size_t)z * M * N;
  const float* bias = (EPI == 0) ? (z == 0 ? bias0 : (z == 1 ? bias1 : bias2)) : nullptr;
  const float scale = (EPI == 0 && z == 0) ? 0.03125f : 1.0f;

  const int tid = threadIdx.x;
  const int wid = tid >> 6, lane = tid & 63;
  const int wr = wid >> 1, wc = wid & 1;
  const int l3 = lane >> 3, sl = lane & 7;
  const int srcslot = sl ^ l3;

  const u16* Ag = A + (size_t)(bm * 128 + wid * 32 + l3) * K + srcslot * 8;
  const u16* Bg = Bt + (size_t)(bn * 128 + wid * 32 + l3) * K + srcslot * 8;
  u16* AsW = &As[wid * 32 * 64];
  u16* BsW = &Bs[wid * 32 * 64];

  f32x4 acc[4][4];
#pragma unroll
  for (int i = 0; i < 4; i++)
#pragma unroll
    for (int j = 0; j < 4; j++) acc[i][j] = (f32x4)(0.f);

  const int fr = lane & 15, kq = lane >> 4;

  for (int kt = 0; kt < K; kt += 64) {
#pragma unroll
    for (int i = 0; i < 4; i++) {
      gload_lds16(Ag + kt + i * 8 * K, AsW + i * 8 * 64);
      gload_lds16(Bg + kt + i * 8 * K, BsW + i * 8 * 64);
    }
    __syncthreads();
#pragma unroll
    for (int ks = 0; ks < 2; ks++) {
      bf16x8 af[4], bfr[4];
#pragma unroll
      for (int i = 0; i < 4; i++) {
        const int ra = wr * 64 + i * 16 + fr;
        af[i] = *(const bf16x8*)&As[ra * 64 + (((ks * 4 + kq) ^ (ra & 7)) * 8)];
        const int rb = wc * 64 + i * 16 + fr;
        bfr[i] = *(const bf16x8*)&Bs[rb * 64 + (((ks * 4 + kq) ^ (rb & 7)) * 8)];
      }
#pragma unroll
      for (int i = 0; i < 4; i++)
#pragma unroll
        for (int j = 0; j < 4; j++)
          acc[i][j] = __builtin_amdgcn_mfma_f32_16x16x32_bf16(af[i], bfr[j], acc[i][j], 0, 0, 0);
    }
    __syncthreads();
  }

  const int rbase = bm * 128 + wr * 64;
  const int cbase = bn * 128 + wc * 64;
#pragma unroll
  for (int i = 0; i < 4; i++)
#pragma unroll
    for (int j = 0; j < 4; j++) {
      const int col = cbase + j * 16 + fr;
#pragma unroll
      for (int r = 0; r < 4; r++) {
        const int row = rbase + i * 16 + kq * 4 + r;
        float v = acc[i][j][r];
        if (EPI == 0) {
          v = (v + bias[col]) * scale;
          Cb[cofs + (size_t)row * N + col] = f2bf(v);
        } else {
          Cf[cofs + (size_t)row * N + col] = v;
        }
      }
    }
}

// ---------- scores: 256x256-tile, BK=64, 8-wave, 8-phase counted-vmcnt ----------
// P = sigmoid(sigmoid(Q*K^T)*mask), Q pre-scaled by 1/32. z = batch.
// Epilogue: per-wave LDS transpose (static indices) -> float4 mask + packed bf16.
// Boundary to epilogue uses __syncthreads(): raw s_barrier is NOT a compiler
// memory fence, and other waves' tail STAGE DMAs land inside this wave's wlds.
__global__ __launch_bounds__(512, 2) void scores256(
    const u16* __restrict__ Qg, const u16* __restrict__ Kg,
    u16* __restrict__ Pg, const float* __restrict__ maskg) {
  constexpr int S = 4096, DK = 1024;
  __shared__ __align__(16) u16 lds[2][2][2][128 * 64];  // 128 KiB

  // T1 bijective XCD swizzle within each batch plane (256 tiles, 256%8==0)
  const int orig = blockIdx.x + (blockIdx.y << 4);
  const int logical = (orig & 7) * 32 + (orig >> 3);
  const int bm = logical >> 4, bn = logical & 15;
  const int z = blockIdx.z;

  const u16* A = Qg + (size_t)z * S * DK;
  const u16* Bt = Kg + (size_t)z * S * DK;
  const float* mask = maskg + (size_t)z * S * S;
  u16* Cb = Pg + (size_t)z * S * S;

  const int tid = threadIdx.x;
  const int wid = tid >> 6, lane = tid & 63;
  const int wr = wid >> 2, wc = wid & 3;      // 2x4 wave grid; wave tile 128x64
  const int fr = lane & 15, kq = lane >> 4;

  const int srow = (wid << 3) + (lane >> 3);  // staging row (+64 per issue)
  const int sslot = lane & 7;
  const int arow0 = bm * 256, brow0 = bn * 256;

  f32x4 acc[8][4];
#pragma unroll
  for (int i = 0; i < 8; i++)
#pragma unroll
    for (int j = 0; j < 4; j++) acc[i][j] = (f32x4)(0.f);
  bf16x8 a_[4][2], b_[4][2];

#define STAGE(bf, ab, hf, kt_) do {                                         \
    const u16* gp_ = (ab) ? Bt : A;                                         \
    const int rb_ = ((ab) ? brow0 : arow0) + (hf) * 128;                    \
    _Pragma("unroll")                                                       \
    for (int ii_ = 0; ii_ < 2; ii_++) {                                     \
      const int row_ = srow + ii_ * 64;                                     \
      const int c8_ = sslot ^ (row_ & 7);                                   \
      gload_lds16(gp_ + (size_t)(rb_ + row_) * DK + (kt_) + c8_ * 8,        \
                  &lds[bf][ab][hf][wid * 512 + ii_ * 4096]);                \
    }                                                                       \
  } while (0)

#define LDA_(bf, i_, kk_)                                                   \
  (*(const bf16x8*)&lds[bf][0][wr][((i_) * 16 + fr) * 64 +                  \
      ((((kk_) * 4 + kq) ^ (((i_) * 16 + fr) & 7)) * 8)])
#define LDB_(bf, j_, kk_)                                                   \
  (*(const bf16x8*)&lds[bf][1][wc >> 1][((wc & 1) * 64 + (j_) * 16 + fr) * 64 + \
      ((((kk_) * 4 + kq) ^ (((wc & 1) * 64 + (j_) * 16 + fr) & 7)) * 8)])

#define DSA(bf, ih) do {                                                    \
    _Pragma("unroll") for (int i_ = 0; i_ < 4; i_++)                        \
    _Pragma("unroll") for (int k_ = 0; k_ < 2; k_++)                        \
      a_[i_][k_] = LDA_(bf, (ih) + i_, k_);                                 \
  } while (0)
#define DSB(bf, jp) do {                                                    \
    _Pragma("unroll") for (int j_ = 0; j_ < 2; j_++)                        \
    _Pragma("unroll") for (int k_ = 0; k_ < 2; k_++)                        \
      b_[(jp) + j_][k_] = LDB_(bf, (jp) + j_, k_);                          \
  } while (0)
#define MF(ih, jp) do {                                                     \
    _Pragma("unroll") for (int i_ = 0; i_ < 4; i_++)                        \
    _Pragma("unroll") for (int j_ = 0; j_ < 2; j_++)                        \
    _Pragma("unroll") for (int k_ = 0; k_ < 2; k_++)                        \
      acc[(ih) + i_][(jp) + j_] = __builtin_amdgcn_mfma_f32_16x16x32_bf16(  \
          a_[i_][k_], b_[(jp) + j_][k_], acc[(ih) + i_][(jp) + j_], 0, 0, 0); \
  } while (0)
#define BAR() __builtin_amdgcn_s_barrier()
#define LGKM0() asm volatile("s_waitcnt lgkmcnt(0)" ::: "memory")
#define VMC4() asm volatile("s_waitcnt vmcnt(4)" ::: "memory")

  // prologue: tile0 full (A0,A1,B0,B1) + tile1 (B0,B1); drain to 4
  STAGE(0, 0, 0, 0); STAGE(0, 0, 1, 0); STAGE(0, 1, 0, 0); STAGE(0, 1, 1, 0);
  STAGE(1, 1, 0, 64); STAGE(1, 1, 1, 64);
  VMC4();
  BAR();

  constexpr int NIT = DK / 128;  // 8 iterations, 2 K-tiles each
#pragma unroll 1
  for (int t = 0; t < NIT; t++) {
    const int ktv = t * 128 + 64;
    const int kt2 = (t * 128 + 128 < DK) ? t * 128 + 128 : DK - 64;  // clamp tail
    const int kt3 = (t * 128 + 192 < DK) ? t * 128 + 192 : DK - 64;

    // --- tile u = 2t (buf0) ---
    DSA(0, 0); DSB(0, 0);
    STAGE(1, 0, 0, ktv);
    BAR(); LGKM0();
    __builtin_amdgcn_s_setprio(1); MF(0, 0); __builtin_amdgcn_s_setprio(0);
    BAR();
    DSB(0, 2);
    STAGE(1, 0, 1, ktv);
    BAR(); LGKM0();
    __builtin_amdgcn_s_setprio(1); MF(0, 2); __builtin_amdgcn_s_setprio(0);
    BAR();
    DSA(0, 4);
    STAGE(0, 1, 0, kt2);
    BAR(); LGKM0();
    __builtin_amdgcn_s_setprio(1); MF(4, 2); __builtin_amdgcn_s_setprio(0);
    BAR();
    STAGE(0, 1, 1, kt2);
    BAR(); LGKM0();
    __builtin_amdgcn_s_setprio(1); MF(4, 0); __builtin_amdgcn_s_setprio(0);
    VMC4();
    BAR();
    // --- tile v = 2t+1 (buf1) ---
    DSA(1, 0); DSB(1, 0);
    STAGE(0, 0, 0, kt2);
    BAR(); LGKM0();
    __builtin_amdgcn_s_setprio(1); MF(0, 0); __builtin_amdgcn_s_setprio(0);
    BAR();
    DSB(1, 2);
    STAGE(0, 0, 1, kt2);
    BAR(); LGKM0();
    __builtin_amdgcn_s_setprio(1); MF(0, 2); __builtin_amdgcn_s_setprio(0);
    BAR();
    DSA(1, 4);
    STAGE(1, 1, 0, kt3);
    BAR(); LGKM0();
    __builtin_amdgcn_s_setprio(1); MF(4, 2); __builtin_amdgcn_s_setprio(0);
    BAR();
    STAGE(1, 1, 1, kt3);
    BAR(); LGKM0();
    __builtin_amdgcn_s_setprio(1); MF(4, 0); __builtin_amdgcn_s_setprio(0);
    VMC4();
    BAR();
  }

  // ---- epilogue boundary: FULL fence + barrier (not raw s_barrier!) ----
  asm volatile("s_waitcnt vmcnt(0)" ::: "memory");
  __syncthreads();  // IR-level memory fence: no LDS op crosses; all waves' DMAs landed
  __builtin_amdgcn_sched_barrier(0);

  float* wlds = (float*)lds + wid * 4096;  // 64x64 f32 per wave (16 KiB)
  const int rr = lane >> 4, cc = lane & 15;
  const int rbase = bm * 256 + wr * 128;
  const int cbase = bn * 256 + wc * 64;

  // p_ MUST be a literal so acc[] indices are compile-time (rule #20).
#define EPIPASS(p_) do {                                                    \
    _Pragma("unroll") for (int ii = 0; ii < 4; ii++)                        \
    _Pragma("unroll") for (int j = 0; j < 4; j++)                           \
    _Pragma("unroll") for (int r = 0; r < 4; r++) {                         \
      const int row = ii * 16 + kq * 4 + r;                                 \
      const int col = (j * 16 + fr) ^ ((row & 7) << 2);                     \
      wlds[row * 64 + col] = acc[(p_) * 4 + ii][j][r];                      \
    }                                                                       \
    _Pragma("unroll 4") for (int rg = 0; rg < 16; rg++) {                   \
      const int row = rg * 4 + rr;                                          \
      const int colp = (cc * 4) ^ ((row & 7) << 2);                         \
      f32x4 s = *(f32x4*)&wlds[row * 64 + colp];                            \
      const int grow = rbase + (p_) * 64 + row;                             \
      const int gcol = cbase + cc * 4;                                      \
      const float4 m = *(const float4*)&mask[(size_t)grow * S + gcol];      \
      union { u16 h[4]; unsigned long long q; } o;                          \
      o.h[0] = f2bf(fsig(fsig(s[0]) * m.x));                                \
      o.h[1] = f2bf(fsig(fsig(s[1]) * m.y));                                \
      o.h[2] = f2bf(fsig(fsig(s[2]) * m.z));                                \
      o.h[3] = f2bf(fsig(fsig(s[3]) * m.w));                                \
      *(unsigned long long*)&Cb[(size_t)grow * S + gcol] = o.q;             \
    }                                                                       \
  } while (0)

  EPIPASS(0);
  __builtin_amdgcn_sched_barrier(0);  // pin pass-0 reads before pass-1 writes
  EPIPASS(1);
#undef EPIPASS
#undef STAGE
#undef LDA_
#undef LDB_
#undef DSA
#undef DSB
#undef MF
#undef BAR
#undef LGKM0
#undef VMC4
}

extern "C" void kernel_launch(void* const* d_in, const int* in_sizes, int n_in,
                              void* d_out, int out_size, void* d_ws, size_t ws_size,
                              hipStream_t stream) {
  const int B = 2, S = 4096, D = 1024;
  const float* hid  = (const float*)d_in[0];
  const float* mask = (const float*)d_in[1];
  const float* Wq = (const float*)d_in[2];
  const float* bq = (const float*)d_in[3];
  const float* Wk = (const float*)d_in[4];
  const float* bk = (const float*)d_in[5];
  const float* Wv = (const float*)d_in[6];
  const float* bv = (const float*)d_in[7];

  const size_t MT = (size_t)B * S * D;  // 8388608
  u16* hbf = (u16*)d_ws;                // MT
  u16* wbf = hbf + MT;                  // 3*D*D
  u16* Qb  = wbf + 3 * (size_t)D * D;   // MT  (Q,K,V contiguous: EPI0 z-offset)
  u16* Kb  = Qb + MT;
  u16* Vb  = Kb + MT;
  u16* VTb = Vb + MT;                   // MT
  u16* Pb  = VTb + MT;                  // B*S*S

  // 1. converts
  cvt_bf16<<<2048, 256, 0, stream>>>((const float4*)hid, hbf, (int)(MT / 4));
  cvt_w3<<<dim3(512, 1, 3), 256, 0, stream>>>(
      (const float4*)Wq, (const float4*)Wk, (const float4*)Wv, wbf, D * D / 4);

  // 2. fused QKV projection
  gemm_bt<0><<<dim3(B * S / 128, D / 128, 3), 256, 0, stream>>>(
      hbf, wbf, Qb, nullptr, bq, bk, bv, B * S, D, D);

  // 3. V transpose per batch
  transpose_bf16<<<dim3(S / 64, D / 64, B), 256, 0, stream>>>(Vb, VTb, S, D);

  // 4. scores (256^2 8-phase + fenced vectorized epilogue), both batches
  scores256<<<dim3(S / 256, S / 256, B), 512, 0, stream>>>(Qb, Kb, Pb, mask);

  // 5. P*V
  gemm_bt<2><<<dim3(S / 128, D / 128, B), 256, 0, stream>>>(
      Pb, VTb, nullptr, (float*)d_out, nullptr, nullptr, nullptr, S, D, S);
}